// Round 4
// baseline (195.873 us; speedup 1.0000x reference)
//
#include <hip/hip_runtime.h>
#include <hip/hip_bf16.h>

// B=4 S=1024 D=1024 H=16 DH=64 -> flat M=4096, attention raw view [64][1024][64]

using u16 = unsigned short;
typedef __attribute__((ext_vector_type(8))) short bf16x8;
typedef __attribute__((ext_vector_type(4))) float f32x4;
typedef __attribute__((ext_vector_type(4))) u16  u16x4;
typedef __attribute__((ext_vector_type(8))) u16  u16x8;

#define AS1C(p) ((const __attribute__((address_space(1))) void*)(p))
#define AS3(p)  ((__attribute__((address_space(3))) void*)(p))

__device__ __forceinline__ u16 f2bf(float f) {
  union { float f; unsigned u; } v; v.f = f;
  unsigned u = v.u;
  return (u16)((u + 0x7fffu + ((u >> 16) & 1u)) >> 16);  // RNE
}

__device__ __forceinline__ f32x4 mfma16(bf16x8 a, bf16x8 b, f32x4 c) {
  return __builtin_amdgcn_mfma_f32_16x16x32_bf16(a, b, c, 0, 0, 0);
}

// ---------------- prep: fp32->bf16 for x and W's, concat biases ----------------
__global__ __launch_bounds__(256) void prep_kernel(
    const float* __restrict__ x,
    const float* __restrict__ wq, const float* __restrict__ wk,
    const float* __restrict__ wv, const float* __restrict__ wo,
    const float* __restrict__ bq, const float* __restrict__ bk, const float* __restrict__ bv,
    u16* __restrict__ xb, u16* __restrict__ wb, float* __restrict__ bc)
{
  int ch = blockIdx.x * 256 + threadIdx.x;
  if (ch < 2097152) {
    const float* src; u16* dst;
    if (ch < 1048576) { src = x + ch * 4; dst = xb + ch * 4; }
    else {
      int c2 = ch - 1048576;
      int wsel = c2 >> 18;
      int off  = c2 & 262143;
      const float* wsrc[4] = { wq, wk, wv, wo };
      src = wsrc[wsel] + off * 4;
      dst = wb + wsel * 1048576 + off * 4;
    }
    f32x4 v = *(const f32x4*)src;
    u16x4 o;
    o[0] = f2bf(v[0]); o[1] = f2bf(v[1]); o[2] = f2bf(v[2]); o[3] = f2bf(v[3]);
    *(u16x4*)dst = o;
  } else {
    int c3 = ch - 2097152;            // < 768
    int bsel = c3 >> 8, off = c3 & 255;
    const float* bsrc[3] = { bq, bk, bv };
    f32x4 v = *(const f32x4*)(bsrc[bsel] + off * 4);
    *(f32x4*)(bc + bsel * 1024 + off * 4) = v;
  }
}

// ---------------- counted-vmcnt pipelined GEMM C = A * W^T ----------------
// 128x128 tile, BK=32, 4 waves (2x2, each 64x64 out). 4 LDS buffers, prefetch dist 2,
// ONE s_barrier + vmcnt(8) per K-step (never 0 in main loop). 64KB LDS -> 2 blocks/CU.
// Chunk swizzle: LDS slot(r,pc) holds global chunk pc ^ ((r>>2)&3); read pc8 = (g^((lr>>2)&3))*8.
// Ledger: STAGE@t targets buf (t+2)&3 (last read @t-2, certified by barrier@t-1);
//         vmcnt(8)+barrier@t certifies tile t landed for all waves.
// MODE 0: out bf16 -> Q*0.125 | K | V^T[64bh][64dh][1024k]; bias=concat[3072].
// MODE 1: out f32 = acc + bias + residual.
template <int MODE, int GM>
__global__ __launch_bounds__(256) void gemm_p4(
    const u16* __restrict__ A, const u16* __restrict__ Bw,
    const float* __restrict__ bias, const float* __restrict__ resid,
    u16* __restrict__ outb, float* __restrict__ outf)
{
  __shared__ u16 As[4][4096];
  __shared__ u16 Bs[4][4096];

  const int K = 1024;
  int tid = threadIdx.x, w = tid >> 6, lane = tid & 63;
  int g = lane >> 4, lr = lane & 15;
  int wr = w >> 1, wcn = w & 1;

  // XCD-bijective block swizzle (grid % 8 == 0)
  int nwg = gridDim.x;
  int cpx = nwg >> 3;
  int bid = blockIdx.x;
  int swz = (bid & 7) * cpx + (bid >> 3);
  int bm = swz % GM, bn = swz / GM;

  // staging: 512 chunks (16B) per operand tile; each thread 2 A + 2 B chunks
  int ch0 = tid, ch1 = tid + 256;
  auto srcoff = [&](int ch) -> size_t {
    int r = ch >> 2, pc = ch & 3;
    int gc = pc ^ ((r >> 2) & 3);        // source pre-swizzle (involution)
    return (size_t)r * K + gc * 8;
  };
  const u16* aS0 = A  + (size_t)(bm * 128) * K + srcoff(ch0);
  const u16* aS1 = A  + (size_t)(bm * 128) * K + srcoff(ch1);
  const u16* bS0 = Bw + (size_t)(bn * 128) * K + srcoff(ch0);
  const u16* bS1 = Bw + (size_t)(bn * 128) * K + srcoff(ch1);
  int lo0 = ch0 * 8, lo1 = ch1 * 8;

  auto STAGE = [&](int buf, int kt) {
    __builtin_amdgcn_global_load_lds(AS1C(aS0 + kt * 32), AS3(&As[buf][lo0]), 16, 0, 0);
    __builtin_amdgcn_global_load_lds(AS1C(aS1 + kt * 32), AS3(&As[buf][lo1]), 16, 0, 0);
    __builtin_amdgcn_global_load_lds(AS1C(bS0 + kt * 32), AS3(&Bs[buf][lo0]), 16, 0, 0);
    __builtin_amdgcn_global_load_lds(AS1C(bS1 + kt * 32), AS3(&Bs[buf][lo1]), 16, 0, 0);
  };

  f32x4 acc[4][4] = {};
  int pc8 = (g ^ ((lr >> 2) & 3)) * 8;   // swizzled read chunk

  auto COMPUTE = [&](int buf) {
    bf16x8 af[4], bfr[4];
#pragma unroll
    for (int m = 0; m < 4; ++m)
      af[m] = *(const bf16x8*)&As[buf][(wr * 64 + m * 16 + lr) * 32 + pc8];
#pragma unroll
    for (int n = 0; n < 4; ++n)
      bfr[n] = *(const bf16x8*)&Bs[buf][(wcn * 64 + n * 16 + lr) * 32 + pc8];
    __builtin_amdgcn_s_setprio(1);
#pragma unroll
    for (int m = 0; m < 4; ++m)
#pragma unroll
      for (int n = 0; n < 4; ++n)
        acc[m][n] = mfma16(af[m], bfr[n], acc[m][n]);
    __builtin_amdgcn_s_setprio(0);
  };

  // prologue: 2 tiles in flight
  STAGE(0, 0); STAGE(1, 1);

  for (int t = 0; t < 30; ++t) {
    STAGE((t + 2) & 3, t + 2);
    asm volatile("s_waitcnt vmcnt(8)" ::: "memory");   // tile t landed; 2 tiles stay in flight
    __builtin_amdgcn_s_barrier();
    COMPUTE(t & 3);
  }
  asm volatile("s_waitcnt vmcnt(4)" ::: "memory");
  __builtin_amdgcn_s_barrier();
  COMPUTE(2);                                           // t=30
  asm volatile("s_waitcnt vmcnt(0)" ::: "memory");
  __builtin_amdgcn_s_barrier();
  COMPUTE(3);                                           // t=31

  // epilogue: D layout col=lane&15, row=(lane>>4)*4+i
#pragma unroll
  for (int m = 0; m < 4; ++m) {
    int row0 = bm * 128 + wr * 64 + m * 16 + 4 * g;
#pragma unroll
    for (int n = 0; n < 4; ++n) {
      int col = bn * 128 + wcn * 64 + n * 16 + lr;
#pragma unroll
      for (int i = 0; i < 4; ++i) {
        float v = acc[m][n][i];
        if (MODE == 0) {
          v += bias[col];
          int r = row0 + i;
          if (col < 1024) {
            outb[(size_t)r * 1024 + col] = f2bf(v * 0.125f);               // Q (scale folded)
          } else if (col < 2048) {
            outb[4194304 + (size_t)r * 1024 + (col - 1024)] = f2bf(v);     // K
          } else {
            int c = col - 2048;
            // V^T[bh=r>>6][dh=c&63][k=(r&63)*16+(c>>6)]
            outb[8388608 + (size_t)(r >> 6) * 65536 + (size_t)(c & 63) * 1024
                 + (r & 63) * 16 + (c >> 6)] = f2bf(v);
          }
        } else {
          size_t idx = (size_t)(row0 + i) * 1024 + col;
          outf[idx] = v + bias[col] + resid[idx];
        }
      }
    }
  }
}

// ---------------- flash attention: raw view [64][1024][64], KV-tile 64, 8 waves ----------------
__global__ __launch_bounds__(512) void attn_kernel(
    const u16* __restrict__ Qb, const u16* __restrict__ Kb,
    const u16* __restrict__ Vtb, u16* __restrict__ Ob)
{
  __shared__ u16 Ks[2][64 * 64];    // [kc][d], chunk-swizzled: LDS[r][c] = glob chunk c^(r&7)
  __shared__ u16 Vts[2][64 * 64];   // [dh][k], same swizzle
  __shared__ u16 Ps[8][16 * 72];    // per-wave P [16 q][64 k], pad 72

  int blk = blockIdx.x;
  int bh = blk & 63, qt = blk >> 6;          // same-head blocks share XCD L2
  int tid = threadIdx.x, wid = tid >> 6, lane = tid & 63;
  int g = lane >> 4, lr = lane & 15;

  const u16* Qp = Qb  + (size_t)bh * 65536;
  const u16* Kp = Kb  + (size_t)bh * 65536;
  const u16* Vp = Vtb + (size_t)bh * 65536;

  // Q fragments: rows qt*128 + wid*16 + lr
  bf16x8 qf[2];
#pragma unroll
  for (int f = 0; f < 2; ++f)
    qf[f] = *(const bf16x8*)&Qp[(size_t)(qt * 128 + wid * 16 + lr) * 64 + f * 32 + 8 * g];

  f32x4 oacc[4] = {};
  float mrow[4], lrowv[4];
#pragma unroll
  for (int i = 0; i < 4; ++i) { mrow[i] = -1e30f; lrowv[i] = 0.f; }

  // staging addresses (512 chunks of 16B per buffer, one instr per thread)
  int kc  = tid >> 3, scc = tid & 7;
  const u16* gkBase = Kp + (size_t)kc * 64 + (size_t)(scc ^ (kc & 7)) * 8;   // + kt*64*64
  const u16* gvBase = Vp + (size_t)kc * 1024 + (size_t)(scc ^ (kc & 7)) * 8; // row=dh, + kt*64

#define STAGE_ATTN(b, kt) do { \
    __builtin_amdgcn_global_load_lds(AS1C(gkBase + (size_t)(kt) * 4096), AS3(&Ks[b][tid * 8]),  16, 0, 0); \
    __builtin_amdgcn_global_load_lds(AS1C(gvBase + (kt) * 64),           AS3(&Vts[b][tid * 8]), 16, 0, 0); \
  } while (0)

  STAGE_ATTN(0, 0);
  __syncthreads();
  int cur = 0;

  for (int kt = 0; kt < 16; ++kt) {
    if (kt + 1 < 16) STAGE_ATTN(cur ^ 1, kt + 1);

    // --- S = Q K^T (Q pre-scaled). s[n][i] = S[4g+i][n*16+lr]
    f32x4 s[4];
#pragma unroll
    for (int n = 0; n < 4; ++n) {
      f32x4 z = { 0.f, 0.f, 0.f, 0.f };
      int kr = n * 16 + lr;
#pragma unroll
      for (int f = 0; f < 2; ++f) {
        bf16x8 kb = *(const bf16x8*)&Ks[cur][kr * 64 + (((f * 4 + g) ^ (kr & 7)) * 8)];
        z = mfma16(qf[f], kb, z);
      }
      s[n] = z;
    }

    // --- online softmax (row = 4g+i, spread over 16 lr-lanes)
    float corr[4], pvv[4][4];
#pragma unroll
    for (int i = 0; i < 4; ++i) {
      float tm = fmaxf(fmaxf(s[0][i], s[1][i]), fmaxf(s[2][i], s[3][i]));
#pragma unroll
      for (int ms = 1; ms < 16; ms <<= 1) tm = fmaxf(tm, __shfl_xor(tm, ms));
      float mn = fmaxf(mrow[i], tm);
      corr[i] = __expf(mrow[i] - mn);
      float rs = 0.f;
#pragma unroll
      for (int n = 0; n < 4; ++n) {
        float p = __expf(s[n][i] - mn);
        pvv[n][i] = p; rs += p;
      }
#pragma unroll
      for (int ms = 1; ms < 16; ms <<= 1) rs += __shfl_xor(rs, ms);
      lrowv[i] = lrowv[i] * corr[i] + rs;
      mrow[i] = mn;
    }
#pragma unroll
    for (int nd = 0; nd < 4; ++nd) {
      f32x4 o = oacc[nd];
      o[0] *= corr[0]; o[1] *= corr[1]; o[2] *= corr[2]; o[3] *= corr[3];
      oacc[nd] = o;
    }

    // --- P -> LDS (wave-local)
#pragma unroll
    for (int n = 0; n < 4; ++n)
#pragma unroll
      for (int i = 0; i < 4; ++i)
        Ps[wid][(4 * g + i) * 72 + n * 16 + lr] = f2bf(pvv[n][i]);
    asm volatile("s_waitcnt lgkmcnt(0)" ::: "memory");

    // --- PV: ctx[q][d] += P[q][k] V^T[d][k]
#pragma unroll
    for (int f = 0; f < 2; ++f) {
      bf16x8 pa = *(const bf16x8*)&Ps[wid][lr * 72 + f * 32 + 8 * g];
#pragma unroll
      for (int nd = 0; nd < 4; ++nd) {
        int dr = nd * 16 + lr;
        bf16x8 vb = *(const bf16x8*)&Vts[cur][dr * 64 + (((f * 4 + g) ^ (dr & 7)) * 8)];
        oacc[nd] = mfma16(pa, vb, oacc[nd]);
      }
    }
    __syncthreads();   // next tile landed (vmcnt0); reads of cur done (lgkm0)
    cur ^= 1;
  }

  // epilogue: ctx = oacc / l
  u16* Op = Ob + (size_t)bh * 65536 + (size_t)(qt * 128 + wid * 16) * 64;
#pragma unroll
  for (int nd = 0; nd < 4; ++nd)
#pragma unroll
    for (int i = 0; i < 4; ++i)
      Op[(4 * g + i) * 64 + nd * 16 + lr] = f2bf(oacc[nd][i] / lrowv[i]);
}

// ---------------- LayerNorm in-place over rows of out [4096][1024] ----------------
__global__ __launch_bounds__(256) void ln_kernel(
    float* __restrict__ out, const float* __restrict__ gamma, const float* __restrict__ beta)
{
  int row = blockIdx.x, tid = threadIdx.x;
  int lane = tid & 63, wid = tid >> 6;
  f32x4 v = *(const f32x4*)&out[(size_t)row * 1024 + tid * 4];
  float s = v[0] + v[1] + v[2] + v[3];
  float q = v[0] * v[0] + v[1] * v[1] + v[2] * v[2] + v[3] * v[3];
#pragma unroll
  for (int ms = 1; ms < 64; ms <<= 1) { s += __shfl_xor(s, ms); q += __shfl_xor(q, ms); }
  __shared__ float red[8];
  if (lane == 0) { red[wid] = s; red[wid + 4] = q; }
  __syncthreads();
  s = red[0] + red[1] + red[2] + red[3];
  q = red[4] + red[5] + red[6] + red[7];
  float mu = s * (1.f / 1024.f);
  float var = q * (1.f / 1024.f) - mu * mu;
  float inv = rsqrtf(var + 1e-5f);
  f32x4 g4 = *(const f32x4*)&gamma[tid * 4];
  f32x4 b4 = *(const f32x4*)&beta[tid * 4];
  f32x4 o;
#pragma unroll
  for (int j = 0; j < 4; ++j) o[j] = (v[j] - mu) * inv * g4[j] + b4[j];
  *(f32x4*)&out[(size_t)row * 1024 + tid * 4] = o;
}

// ---------------- launch ----------------
extern "C" void kernel_launch(void* const* d_in, const int* in_sizes, int n_in,
                              void* d_out, int out_size, void* d_ws, size_t ws_size,
                              hipStream_t stream) {
  const float* x     = (const float*)d_in[0];
  const float* Wq    = (const float*)d_in[1];
  const float* bq    = (const float*)d_in[2];
  const float* Wk    = (const float*)d_in[3];
  const float* bk    = (const float*)d_in[4];
  const float* Wv    = (const float*)d_in[5];
  const float* bv    = (const float*)d_in[6];
  const float* Wo    = (const float*)d_in[7];
  const float* bo    = (const float*)d_in[8];
  const float* gamma = (const float*)d_in[9];
  const float* beta  = (const float*)d_in[10];
  float* out = (float*)d_out;

  char* ws = (char*)d_ws;
  u16*   xb  = (u16*)ws;                                   // 8MB  [4096][1024] bf16 (reused as ctx)
  u16*   wb  = (u16*)(ws + (8u << 20));                    // 8MB  Wq|Wk|Wv|Wo bf16
  float* bc  = (float*)(ws + (16u << 20));                 // 12KB bq|bk|bv
  u16*   qkv = (u16*)(ws + (16u << 20) + 16384);           // 24MB Q | K | V^T bf16
  u16*   ctx = xb;                                         // overlay: xb dead after QKV GEMM

  prep_kernel<<<8195, 256, 0, stream>>>(x, Wq, Wk, Wv, Wo, bq, bk, bv, xb, wb, bc);

  // QKV: M=4096 x N=3072 -> grid 32x24 = 768 blocks (1D, XCD-swizzled inside)
  gemm_p4<0, 32><<<768, 256, 0, stream>>>(xb, wb, bc, nullptr, qkv, nullptr);

  attn_kernel<<<512, 512, 0, stream>>>(qkv, qkv + 4194304, qkv + 8388608, ctx);

  // out-proj: M=4096 x N=1024 -> grid 32x8 = 256 blocks
  gemm_p4<1, 32><<<256, 256, 0, stream>>>(ctx, wb + 3 * 1048576, bo, x, nullptr, out);

  ln_kernel<<<4096, 256, 0, stream>>>(out, gamma, beta);
}

// Round 5
// 154.207 us; speedup vs baseline: 1.2702x; 1.2702x over previous
//
#include <hip/hip_runtime.h>
#include <hip/hip_bf16.h>

// B=4 S=1024 D=1024 H=16 DH=64 -> flat M=4096, attention raw view [64][1024][64]

using u16 = unsigned short;
typedef __attribute__((ext_vector_type(8))) short bf16x8;
typedef __attribute__((ext_vector_type(4))) float f32x4;
typedef __attribute__((ext_vector_type(4))) u16  u16x4;
typedef __attribute__((ext_vector_type(8))) u16  u16x8;

#define AS1C(p) ((const __attribute__((address_space(1))) void*)(p))
#define AS3(p)  ((__attribute__((address_space(3))) void*)(p))

__device__ __forceinline__ u16 f2bf(float f) {
  union { float f; unsigned u; } v; v.f = f;
  unsigned u = v.u;
  return (u16)((u + 0x7fffu + ((u >> 16) & 1u)) >> 16);  // RNE
}

__device__ __forceinline__ f32x4 mfma16(bf16x8 a, bf16x8 b, f32x4 c) {
  return __builtin_amdgcn_mfma_f32_16x16x32_bf16(a, b, c, 0, 0, 0);
}

// ---------------- prep: fp32->bf16 for x and W's, concat biases ----------------
__global__ __launch_bounds__(256) void prep_kernel(
    const float* __restrict__ x,
    const float* __restrict__ wq, const float* __restrict__ wk,
    const float* __restrict__ wv, const float* __restrict__ wo,
    const float* __restrict__ bq, const float* __restrict__ bk, const float* __restrict__ bv,
    u16* __restrict__ xb, u16* __restrict__ wb, float* __restrict__ bc)
{
  int ch = blockIdx.x * 256 + threadIdx.x;
  if (ch < 2097152) {
    const float* src; u16* dst;
    if (ch < 1048576) { src = x + ch * 4; dst = xb + ch * 4; }
    else {
      int c2 = ch - 1048576;
      int wsel = c2 >> 18;
      int off  = c2 & 262143;
      const float* wsrc[4] = { wq, wk, wv, wo };
      src = wsrc[wsel] + off * 4;
      dst = wb + wsel * 1048576 + off * 4;
    }
    f32x4 v = *(const f32x4*)src;
    u16x4 o;
    o[0] = f2bf(v[0]); o[1] = f2bf(v[1]); o[2] = f2bf(v[2]); o[3] = f2bf(v[3]);
    *(u16x4*)dst = o;
  } else {
    int c3 = ch - 2097152;            // < 768
    int bsel = c3 >> 8, off = c3 & 255;
    const float* bsrc[3] = { bq, bk, bv };
    f32x4 v = *(const f32x4*)(bsrc[bsel] + off * 4);
    *(f32x4*)(bc + bsel * 1024 + off * 4) = v;
  }
}

// ---------------- counted-vmcnt pipelined GEMM C = A * W^T ----------------
// 128x128 tile, BK=32, 4 waves (2x2, each 64x64 out). 4 LDS buffers, prefetch dist 2,
// ONE s_barrier + vmcnt(8) per K-step (never 0 in main loop). 64KB LDS -> 2 blocks/CU.
// Block mapping: bm = (bid&7)+8*((bid>>3)&3), bn = bid>>5. With round-robin XCD=bid%8,
// all blocks sharing a bm (the 8 writers of each V^T 128B line, bids bm+32*bn) land on
// XCD bm%8 -> partial V^T lines merge in ONE XCD's L2 (round-2's accidental property;
// losing it caused round-3/4's 3x write amplification).
// Ledger: STAGE@t targets buf (t+2)&3 (last read @t-2, certified by barrier@t-1);
//         vmcnt(8)+barrier@t certifies tile t landed for all waves.
// MODE 0: out bf16 -> Q*0.125 | K | V^T[64bh][64dh][1024k]; bias=concat[3072].
// MODE 1: out f32 = acc + bias + residual.
template <int MODE>
__global__ __launch_bounds__(256) void gemm_p4(
    const u16* __restrict__ A, const u16* __restrict__ Bw,
    const float* __restrict__ bias, const float* __restrict__ resid,
    u16* __restrict__ outb, float* __restrict__ outf)
{
  __shared__ u16 As[4][4096];
  __shared__ u16 Bs[4][4096];

  const int K = 1024;
  int tid = threadIdx.x, w = tid >> 6, lane = tid & 63;
  int g = lane >> 4, lr = lane & 15;
  int wr = w >> 1, wcn = w & 1;

  // V^T-line-coherent block mapping (see header comment)
  int bid = blockIdx.x;
  int bm = (bid & 7) + 8 * ((bid >> 3) & 3);
  int bn = bid >> 5;

  // staging: 512 chunks (16B) per operand tile; each thread 2 A + 2 B chunks
  int ch0 = tid, ch1 = tid + 256;
  auto srcoff = [&](int ch) -> size_t {
    int r = ch >> 2, pc = ch & 3;
    int gc = pc ^ ((r >> 2) & 3);        // source pre-swizzle (involution)
    return (size_t)r * K + gc * 8;
  };
  const u16* aS0 = A  + (size_t)(bm * 128) * K + srcoff(ch0);
  const u16* aS1 = A  + (size_t)(bm * 128) * K + srcoff(ch1);
  const u16* bS0 = Bw + (size_t)(bn * 128) * K + srcoff(ch0);
  const u16* bS1 = Bw + (size_t)(bn * 128) * K + srcoff(ch1);
  int lo0 = ch0 * 8, lo1 = ch1 * 8;

  auto STAGE = [&](int buf, int kt) {
    __builtin_amdgcn_global_load_lds(AS1C(aS0 + kt * 32), AS3(&As[buf][lo0]), 16, 0, 0);
    __builtin_amdgcn_global_load_lds(AS1C(aS1 + kt * 32), AS3(&As[buf][lo1]), 16, 0, 0);
    __builtin_amdgcn_global_load_lds(AS1C(bS0 + kt * 32), AS3(&Bs[buf][lo0]), 16, 0, 0);
    __builtin_amdgcn_global_load_lds(AS1C(bS1 + kt * 32), AS3(&Bs[buf][lo1]), 16, 0, 0);
  };

  f32x4 acc[4][4] = {};
  int pc8 = (g ^ ((lr >> 2) & 3)) * 8;   // swizzled read chunk

  auto COMPUTE = [&](int buf) {
    bf16x8 af[4], bfr[4];
#pragma unroll
    for (int m = 0; m < 4; ++m)
      af[m] = *(const bf16x8*)&As[buf][(wr * 64 + m * 16 + lr) * 32 + pc8];
#pragma unroll
    for (int n = 0; n < 4; ++n)
      bfr[n] = *(const bf16x8*)&Bs[buf][(wcn * 64 + n * 16 + lr) * 32 + pc8];
    __builtin_amdgcn_s_setprio(1);
#pragma unroll
    for (int m = 0; m < 4; ++m)
#pragma unroll
      for (int n = 0; n < 4; ++n)
        acc[m][n] = mfma16(af[m], bfr[n], acc[m][n]);
    __builtin_amdgcn_s_setprio(0);
  };

  // prologue: 2 tiles in flight
  STAGE(0, 0); STAGE(1, 1);

  for (int t = 0; t < 30; ++t) {
    STAGE((t + 2) & 3, t + 2);
    asm volatile("s_waitcnt vmcnt(8)" ::: "memory");   // tile t landed; 2 tiles stay in flight
    __builtin_amdgcn_s_barrier();
    COMPUTE(t & 3);
  }
  asm volatile("s_waitcnt vmcnt(4)" ::: "memory");
  __builtin_amdgcn_s_barrier();
  COMPUTE(2);                                           // t=30
  asm volatile("s_waitcnt vmcnt(0)" ::: "memory");
  __builtin_amdgcn_s_barrier();
  COMPUTE(3);                                           // t=31

  // epilogue: D layout col=lane&15, row=(lane>>4)*4+i
#pragma unroll
  for (int m = 0; m < 4; ++m) {
    int row0 = bm * 128 + wr * 64 + m * 16 + 4 * g;
#pragma unroll
    for (int n = 0; n < 4; ++n) {
      int col = bn * 128 + wcn * 64 + n * 16 + lr;
#pragma unroll
      for (int i = 0; i < 4; ++i) {
        float v = acc[m][n][i];
        if (MODE == 0) {
          v += bias[col];
          int r = row0 + i;
          if (col < 1024) {
            outb[(size_t)r * 1024 + col] = f2bf(v * 0.125f);               // Q (scale folded)
          } else if (col < 2048) {
            outb[4194304 + (size_t)r * 1024 + (col - 1024)] = f2bf(v);     // K
          } else {
            int c = col - 2048;
            // V^T[bh=r>>6][dh=c&63][k=(r&63)*16+(c>>6)]
            outb[8388608 + (size_t)(r >> 6) * 65536 + (size_t)(c & 63) * 1024
                 + (r & 63) * 16 + (c >> 6)] = f2bf(v);
          }
        } else {
          size_t idx = (size_t)(row0 + i) * 1024 + col;
          outf[idx] = v + bias[col] + resid[idx];
        }
      }
    }
  }
}

// ---------------- flash attention: raw view [64][1024][64], KV-tile 64, 8 waves ----------------
__global__ __launch_bounds__(512) void attn_kernel(
    const u16* __restrict__ Qb, const u16* __restrict__ Kb,
    const u16* __restrict__ Vtb, u16* __restrict__ Ob)
{
  __shared__ u16 Ks[2][64 * 64];    // [kc][d], chunk-swizzled: LDS[r][c] = glob chunk c^(r&7)
  __shared__ u16 Vts[2][64 * 64];   // [dh][k], same swizzle
  __shared__ u16 Ps[8][16 * 72];    // per-wave P [16 q][64 k], pad 72

  int blk = blockIdx.x;
  int bh = blk & 63, qt = blk >> 6;          // same-head blocks share XCD L2
  int tid = threadIdx.x, wid = tid >> 6, lane = tid & 63;
  int g = lane >> 4, lr = lane & 15;

  const u16* Qp = Qb  + (size_t)bh * 65536;
  const u16* Kp = Kb  + (size_t)bh * 65536;
  const u16* Vp = Vtb + (size_t)bh * 65536;

  // Q fragments: rows qt*128 + wid*16 + lr
  bf16x8 qf[2];
#pragma unroll
  for (int f = 0; f < 2; ++f)
    qf[f] = *(const bf16x8*)&Qp[(size_t)(qt * 128 + wid * 16 + lr) * 64 + f * 32 + 8 * g];

  f32x4 oacc[4] = {};
  float mrow[4], lrowv[4];
#pragma unroll
  for (int i = 0; i < 4; ++i) { mrow[i] = -1e30f; lrowv[i] = 0.f; }

  // staging addresses (512 chunks of 16B per buffer, one instr per thread)
  int kc  = tid >> 3, scc = tid & 7;
  const u16* gkBase = Kp + (size_t)kc * 64 + (size_t)(scc ^ (kc & 7)) * 8;   // + kt*64*64
  const u16* gvBase = Vp + (size_t)kc * 1024 + (size_t)(scc ^ (kc & 7)) * 8; // row=dh, + kt*64

#define STAGE_ATTN(b, kt) do { \
    __builtin_amdgcn_global_load_lds(AS1C(gkBase + (size_t)(kt) * 4096), AS3(&Ks[b][tid * 8]),  16, 0, 0); \
    __builtin_amdgcn_global_load_lds(AS1C(gvBase + (kt) * 64),           AS3(&Vts[b][tid * 8]), 16, 0, 0); \
  } while (0)

  STAGE_ATTN(0, 0);
  __syncthreads();
  int cur = 0;

  for (int kt = 0; kt < 16; ++kt) {
    if (kt + 1 < 16) STAGE_ATTN(cur ^ 1, kt + 1);

    // --- S = Q K^T (Q pre-scaled). s[n][i] = S[4g+i][n*16+lr]
    f32x4 s[4];
#pragma unroll
    for (int n = 0; n < 4; ++n) {
      f32x4 z = { 0.f, 0.f, 0.f, 0.f };
      int kr = n * 16 + lr;
#pragma unroll
      for (int f = 0; f < 2; ++f) {
        bf16x8 kb = *(const bf16x8*)&Ks[cur][kr * 64 + (((f * 4 + g) ^ (kr & 7)) * 8)];
        z = mfma16(qf[f], kb, z);
      }
      s[n] = z;
    }

    // --- online softmax (row = 4g+i, spread over 16 lr-lanes)
    float corr[4], pvv[4][4];
#pragma unroll
    for (int i = 0; i < 4; ++i) {
      float tm = fmaxf(fmaxf(s[0][i], s[1][i]), fmaxf(s[2][i], s[3][i]));
#pragma unroll
      for (int ms = 1; ms < 16; ms <<= 1) tm = fmaxf(tm, __shfl_xor(tm, ms));
      float mn = fmaxf(mrow[i], tm);
      corr[i] = __expf(mrow[i] - mn);
      float rs = 0.f;
#pragma unroll
      for (int n = 0; n < 4; ++n) {
        float p = __expf(s[n][i] - mn);
        pvv[n][i] = p; rs += p;
      }
#pragma unroll
      for (int ms = 1; ms < 16; ms <<= 1) rs += __shfl_xor(rs, ms);
      lrowv[i] = lrowv[i] * corr[i] + rs;
      mrow[i] = mn;
    }
#pragma unroll
    for (int nd = 0; nd < 4; ++nd) {
      f32x4 o = oacc[nd];
      o[0] *= corr[0]; o[1] *= corr[1]; o[2] *= corr[2]; o[3] *= corr[3];
      oacc[nd] = o;
    }

    // --- P -> LDS (wave-local)
#pragma unroll
    for (int n = 0; n < 4; ++n)
#pragma unroll
      for (int i = 0; i < 4; ++i)
        Ps[wid][(4 * g + i) * 72 + n * 16 + lr] = f2bf(pvv[n][i]);
    asm volatile("s_waitcnt lgkmcnt(0)" ::: "memory");

    // --- PV: ctx[q][d] += P[q][k] V^T[d][k]
#pragma unroll
    for (int f = 0; f < 2; ++f) {
      bf16x8 pa = *(const bf16x8*)&Ps[wid][lr * 72 + f * 32 + 8 * g];
#pragma unroll
      for (int nd = 0; nd < 4; ++nd) {
        int dr = nd * 16 + lr;
        bf16x8 vb = *(const bf16x8*)&Vts[cur][dr * 64 + (((f * 4 + g) ^ (dr & 7)) * 8)];
        oacc[nd] = mfma16(pa, vb, oacc[nd]);
      }
    }
    __syncthreads();   // next tile landed (vmcnt0); reads of cur done (lgkm0)
    cur ^= 1;
  }

  // epilogue: ctx = oacc / l
  u16* Op = Ob + (size_t)bh * 65536 + (size_t)(qt * 128 + wid * 16) * 64;
#pragma unroll
  for (int nd = 0; nd < 4; ++nd)
#pragma unroll
    for (int i = 0; i < 4; ++i)
      Op[(4 * g + i) * 64 + nd * 16 + lr] = f2bf(oacc[nd][i] / lrowv[i]);
}

// ---------------- LayerNorm in-place over rows of out [4096][1024] ----------------
__global__ __launch_bounds__(256) void ln_kernel(
    float* __restrict__ out, const float* __restrict__ gamma, const float* __restrict__ beta)
{
  int row = blockIdx.x, tid = threadIdx.x;
  int lane = tid & 63, wid = tid >> 6;
  f32x4 v = *(const f32x4*)&out[(size_t)row * 1024 + tid * 4];
  float s = v[0] + v[1] + v[2] + v[3];
  float q = v[0] * v[0] + v[1] * v[1] + v[2] * v[2] + v[3] * v[3];
#pragma unroll
  for (int ms = 1; ms < 64; ms <<= 1) { s += __shfl_xor(s, ms); q += __shfl_xor(q, ms); }
  __shared__ float red[8];
  if (lane == 0) { red[wid] = s; red[wid + 4] = q; }
  __syncthreads();
  s = red[0] + red[1] + red[2] + red[3];
  q = red[4] + red[5] + red[6] + red[7];
  float mu = s * (1.f / 1024.f);
  float var = q * (1.f / 1024.f) - mu * mu;
  float inv = rsqrtf(var + 1e-5f);
  f32x4 g4 = *(const f32x4*)&gamma[tid * 4];
  f32x4 b4 = *(const f32x4*)&beta[tid * 4];
  f32x4 o;
#pragma unroll
  for (int j = 0; j < 4; ++j) o[j] = (v[j] - mu) * inv * g4[j] + b4[j];
  *(f32x4*)&out[(size_t)row * 1024 + tid * 4] = o;
}

// ---------------- launch ----------------
extern "C" void kernel_launch(void* const* d_in, const int* in_sizes, int n_in,
                              void* d_out, int out_size, void* d_ws, size_t ws_size,
                              hipStream_t stream) {
  const float* x     = (const float*)d_in[0];
  const float* Wq    = (const float*)d_in[1];
  const float* bq    = (const float*)d_in[2];
  const float* Wk    = (const float*)d_in[3];
  const float* bk    = (const float*)d_in[4];
  const float* Wv    = (const float*)d_in[5];
  const float* bv    = (const float*)d_in[6];
  const float* Wo    = (const float*)d_in[7];
  const float* bo    = (const float*)d_in[8];
  const float* gamma = (const float*)d_in[9];
  const float* beta  = (const float*)d_in[10];
  float* out = (float*)d_out;

  char* ws = (char*)d_ws;
  u16*   xb  = (u16*)ws;                                   // 8MB  [4096][1024] bf16 (reused as ctx)
  u16*   wb  = (u16*)(ws + (8u << 20));                    // 8MB  Wq|Wk|Wv|Wo bf16
  float* bc  = (float*)(ws + (16u << 20));                 // 12KB bq|bk|bv
  u16*   qkv = (u16*)(ws + (16u << 20) + 16384);           // 24MB Q | K | V^T bf16
  u16*   ctx = xb;                                         // overlay: xb dead after QKV GEMM

  prep_kernel<<<8195, 256, 0, stream>>>(x, Wq, Wk, Wv, Wo, bq, bk, bv, xb, wb, bc);

  // QKV: M=4096 x N=3072 -> grid 768 (bm=(bid&7)+8*((bid>>3)&3), bn=bid>>5)
  gemm_p4<0><<<768, 256, 0, stream>>>(xb, wb, bc, nullptr, qkv, nullptr);

  attn_kernel<<<512, 512, 0, stream>>>(qkv, qkv + 4194304, qkv + 8388608, ctx);

  // out-proj: M=4096 x N=1024 -> grid 256
  gemm_p4<1><<<256, 256, 0, stream>>>(ctx, wb + 3 * 1048576, bo, x, nullptr, out);

  ln_kernel<<<4096, 256, 0, stream>>>(out, gamma, beta);
}

// Round 6
// 145.864 us; speedup vs baseline: 1.3428x; 1.0572x over previous
//
#include <hip/hip_runtime.h>
#include <hip/hip_bf16.h>

// B=4 S=1024 D=1024 H=16 DH=64 -> flat M=4096, attention raw view [64][1024][64]

using u16 = unsigned short;
typedef __attribute__((ext_vector_type(8))) short bf16x8;
typedef __attribute__((ext_vector_type(4))) float f32x4;
typedef __attribute__((ext_vector_type(4))) u16  u16x4;
typedef __attribute__((ext_vector_type(8))) u16  u16x8;

#define AS1C(p) ((const __attribute__((address_space(1))) void*)(p))
#define AS3(p)  ((__attribute__((address_space(3))) void*)(p))

__device__ __forceinline__ u16 f2bf(float f) {
  union { float f; unsigned u; } v; v.f = f;
  unsigned u = v.u;
  return (u16)((u + 0x7fffu + ((u >> 16) & 1u)) >> 16);  // RNE
}

__device__ __forceinline__ f32x4 mfma16(bf16x8 a, bf16x8 b, f32x4 c) {
  return __builtin_amdgcn_mfma_f32_16x16x32_bf16(a, b, c, 0, 0, 0);
}

// ---------------- prep: fp32->bf16 for x and W's, concat biases ----------------
__global__ __launch_bounds__(256) void prep_kernel(
    const float* __restrict__ x,
    const float* __restrict__ wq, const float* __restrict__ wk,
    const float* __restrict__ wv, const float* __restrict__ wo,
    const float* __restrict__ bq, const float* __restrict__ bk, const float* __restrict__ bv,
    u16* __restrict__ xb, u16* __restrict__ wb, float* __restrict__ bc)
{
  int ch = blockIdx.x * 256 + threadIdx.x;
  if (ch < 2097152) {
    const float* src; u16* dst;
    if (ch < 1048576) { src = x + ch * 4; dst = xb + ch * 4; }
    else {
      int c2 = ch - 1048576;
      int wsel = c2 >> 18;
      int off  = c2 & 262143;
      const float* wsrc[4] = { wq, wk, wv, wo };
      src = wsrc[wsel] + off * 4;
      dst = wb + wsel * 1048576 + off * 4;
    }
    f32x4 v = *(const f32x4*)src;
    u16x4 o;
    o[0] = f2bf(v[0]); o[1] = f2bf(v[1]); o[2] = f2bf(v[2]); o[3] = f2bf(v[3]);
    *(u16x4*)dst = o;
  } else {
    int c3 = ch - 2097152;            // < 768
    int bsel = c3 >> 8, off = c3 & 255;
    const float* bsrc[3] = { bq, bk, bv };
    f32x4 v = *(const f32x4*)(bsrc[bsel] + off * 4);
    *(f32x4*)(bc + bsel * 1024 + off * 4) = v;
  }
}

// ---------------- counted-vmcnt pipelined GEMM C = A * W^T ----------------
// 128x128 tile, BK=32, 4 waves (2x2, each 64x64 out). 3 LDS buffers (48KB -> 3 blocks/CU,
// 12 waves/CU), prefetch dist 2, per K-step: vmcnt(4) -> s_barrier -> STAGE(t+2) -> COMPUTE(t).
// vmcnt(4): own tile-t loads landed (only t+1's 4 instrs remain); barrier certifies all waves.
// WAR: STAGE@t writes buf (t+2)%3 == (t-1)%3, whose reads finished before barrier@t.
// vmcnt never drains to 0 in the main loop (peeled last tile only).
// Block mapping: bm=(bid&7)+8*((bid>>3)&3), bn=bid>>5 -> all 8 writers of each V^T 128B
// line (bids bm+32*bn) land on XCD bm%8 -> partial lines merge in one L2 (round-5 proven).
// MODE 0: out bf16 -> Q*0.125 | K | V^T[64bh][64dh][1024k]; bias=concat[3072].
// MODE 1: out f32 = acc + bias + residual.
template <int MODE>
__global__ __launch_bounds__(256) void gemm_p4(
    const u16* __restrict__ A, const u16* __restrict__ Bw,
    const float* __restrict__ bias, const float* __restrict__ resid,
    u16* __restrict__ outb, float* __restrict__ outf)
{
  __shared__ u16 As[3][4096];
  __shared__ u16 Bs[3][4096];

  const int K = 1024;
  int tid = threadIdx.x, w = tid >> 6, lane = tid & 63;
  int g = lane >> 4, lr = lane & 15;
  int wr = w >> 1, wcn = w & 1;

  // V^T-line-coherent block mapping (see header comment)
  int bid = blockIdx.x;
  int bm = (bid & 7) + 8 * ((bid >> 3) & 3);
  int bn = bid >> 5;

  // staging: 512 chunks (16B) per operand tile; each thread 2 A + 2 B chunks
  int ch0 = tid, ch1 = tid + 256;
  auto srcoff = [&](int ch) -> size_t {
    int r = ch >> 2, pc = ch & 3;
    int gc = pc ^ ((r >> 2) & 3);        // source pre-swizzle (involution)
    return (size_t)r * K + gc * 8;
  };
  const u16* aS0 = A  + (size_t)(bm * 128) * K + srcoff(ch0);
  const u16* aS1 = A  + (size_t)(bm * 128) * K + srcoff(ch1);
  const u16* bS0 = Bw + (size_t)(bn * 128) * K + srcoff(ch0);
  const u16* bS1 = Bw + (size_t)(bn * 128) * K + srcoff(ch1);
  int lo0 = ch0 * 8, lo1 = ch1 * 8;

  auto STAGE = [&](int buf, int kt) {
    __builtin_amdgcn_global_load_lds(AS1C(aS0 + kt * 32), AS3(&As[buf][lo0]), 16, 0, 0);
    __builtin_amdgcn_global_load_lds(AS1C(aS1 + kt * 32), AS3(&As[buf][lo1]), 16, 0, 0);
    __builtin_amdgcn_global_load_lds(AS1C(bS0 + kt * 32), AS3(&Bs[buf][lo0]), 16, 0, 0);
    __builtin_amdgcn_global_load_lds(AS1C(bS1 + kt * 32), AS3(&Bs[buf][lo1]), 16, 0, 0);
  };

  f32x4 acc[4][4] = {};
  int pc8 = (g ^ ((lr >> 2) & 3)) * 8;   // swizzled read chunk

  auto COMPUTE = [&](int buf) {
    bf16x8 af[4], bfr[4];
#pragma unroll
    for (int m = 0; m < 4; ++m)
      af[m] = *(const bf16x8*)&As[buf][(wr * 64 + m * 16 + lr) * 32 + pc8];
#pragma unroll
    for (int n = 0; n < 4; ++n)
      bfr[n] = *(const bf16x8*)&Bs[buf][(wcn * 64 + n * 16 + lr) * 32 + pc8];
    __builtin_amdgcn_s_setprio(1);
#pragma unroll
    for (int m = 0; m < 4; ++m)
#pragma unroll
      for (int n = 0; n < 4; ++n)
        acc[m][n] = mfma16(af[m], bfr[n], acc[m][n]);
    __builtin_amdgcn_s_setprio(0);
  };

  // prologue: 2 tiles in flight
  STAGE(0, 0); STAGE(1, 1);

  int sb = 2;                              // buffer for STAGE target (t+2)%3
  int cb = 0;                              // buffer for COMPUTE (t)%3
  for (int t = 0; t < 31; ++t) {
    asm volatile("s_waitcnt vmcnt(4)" ::: "memory");  // tile t landed; t+1 in flight
    __builtin_amdgcn_s_barrier();
    asm volatile("" ::: "memory");                    // no ds_read hoists above barrier
    if (t < 30) {
      STAGE(sb, t + 2);
      if (++sb == 3) sb = 0;
    }
    COMPUTE(cb);
    if (++cb == 3) cb = 0;
  }
  asm volatile("s_waitcnt vmcnt(0)" ::: "memory");    // peeled last tile (t=31)
  __builtin_amdgcn_s_barrier();
  asm volatile("" ::: "memory");
  COMPUTE(cb);

  // epilogue: D layout col=lane&15, row=(lane>>4)*4+i
#pragma unroll
  for (int m = 0; m < 4; ++m) {
    int row0 = bm * 128 + wr * 64 + m * 16 + 4 * g;
#pragma unroll
    for (int n = 0; n < 4; ++n) {
      int col = bn * 128 + wcn * 64 + n * 16 + lr;
#pragma unroll
      for (int i = 0; i < 4; ++i) {
        float v = acc[m][n][i];
        if (MODE == 0) {
          v += bias[col];
          int r = row0 + i;
          if (col < 1024) {
            outb[(size_t)r * 1024 + col] = f2bf(v * 0.125f);               // Q (scale folded)
          } else if (col < 2048) {
            outb[4194304 + (size_t)r * 1024 + (col - 1024)] = f2bf(v);     // K
          } else {
            int c = col - 2048;
            // V^T[bh=r>>6][dh=c&63][k=(r&63)*16+(c>>6)]
            outb[8388608 + (size_t)(r >> 6) * 65536 + (size_t)(c & 63) * 1024
                 + (r & 63) * 16 + (c >> 6)] = f2bf(v);
          }
        } else {
          size_t idx = (size_t)(row0 + i) * 1024 + col;
          outf[idx] = v + bias[col] + resid[idx];
        }
      }
    }
  }
}

// ---------------- flash attention: raw view [64][1024][64], KV-tile 64, 8 waves ----------------
__global__ __launch_bounds__(512) void attn_kernel(
    const u16* __restrict__ Qb, const u16* __restrict__ Kb,
    const u16* __restrict__ Vtb, u16* __restrict__ Ob)
{
  __shared__ u16 Ks[2][64 * 64];    // [kc][d], chunk-swizzled: LDS[r][c] = glob chunk c^(r&7)
  __shared__ u16 Vts[2][64 * 64];   // [dh][k], same swizzle
  __shared__ u16 Ps[8][16 * 72];    // per-wave P [16 q][64 k], pad 72

  int blk = blockIdx.x;
  int bh = blk & 63, qt = blk >> 6;          // same-head blocks share XCD L2
  int tid = threadIdx.x, wid = tid >> 6, lane = tid & 63;
  int g = lane >> 4, lr = lane & 15;

  const u16* Qp = Qb  + (size_t)bh * 65536;
  const u16* Kp = Kb  + (size_t)bh * 65536;
  const u16* Vp = Vtb + (size_t)bh * 65536;

  // Q fragments: rows qt*128 + wid*16 + lr
  bf16x8 qf[2];
#pragma unroll
  for (int f = 0; f < 2; ++f)
    qf[f] = *(const bf16x8*)&Qp[(size_t)(qt * 128 + wid * 16 + lr) * 64 + f * 32 + 8 * g];

  f32x4 oacc[4] = {};
  float mrow[4], lrowv[4];
#pragma unroll
  for (int i = 0; i < 4; ++i) { mrow[i] = -1e30f; lrowv[i] = 0.f; }

  // staging addresses (512 chunks of 16B per buffer, one instr per thread)
  int kc  = tid >> 3, scc = tid & 7;
  const u16* gkBase = Kp + (size_t)kc * 64 + (size_t)(scc ^ (kc & 7)) * 8;   // + kt*64*64
  const u16* gvBase = Vp + (size_t)kc * 1024 + (size_t)(scc ^ (kc & 7)) * 8; // row=dh, + kt*64

#define STAGE_ATTN(b, kt) do { \
    __builtin_amdgcn_global_load_lds(AS1C(gkBase + (size_t)(kt) * 4096), AS3(&Ks[b][tid * 8]),  16, 0, 0); \
    __builtin_amdgcn_global_load_lds(AS1C(gvBase + (kt) * 64),           AS3(&Vts[b][tid * 8]), 16, 0, 0); \
  } while (0)

  STAGE_ATTN(0, 0);
  __syncthreads();
  int cur = 0;

  for (int kt = 0; kt < 16; ++kt) {
    if (kt + 1 < 16) STAGE_ATTN(cur ^ 1, kt + 1);

    // --- S = Q K^T (Q pre-scaled). s[n][i] = S[4g+i][n*16+lr]
    f32x4 s[4];
#pragma unroll
    for (int n = 0; n < 4; ++n) {
      f32x4 z = { 0.f, 0.f, 0.f, 0.f };
      int kr = n * 16 + lr;
#pragma unroll
      for (int f = 0; f < 2; ++f) {
        bf16x8 kb = *(const bf16x8*)&Ks[cur][kr * 64 + (((f * 4 + g) ^ (kr & 7)) * 8)];
        z = mfma16(qf[f], kb, z);
      }
      s[n] = z;
    }

    // --- online softmax (row = 4g+i, spread over 16 lr-lanes)
    float corr[4], pvv[4][4];
#pragma unroll
    for (int i = 0; i < 4; ++i) {
      float tm = fmaxf(fmaxf(s[0][i], s[1][i]), fmaxf(s[2][i], s[3][i]));
#pragma unroll
      for (int ms = 1; ms < 16; ms <<= 1) tm = fmaxf(tm, __shfl_xor(tm, ms));
      float mn = fmaxf(mrow[i], tm);
      corr[i] = __expf(mrow[i] - mn);
      float rs = 0.f;
#pragma unroll
      for (int n = 0; n < 4; ++n) {
        float p = __expf(s[n][i] - mn);
        pvv[n][i] = p; rs += p;
      }
#pragma unroll
      for (int ms = 1; ms < 16; ms <<= 1) rs += __shfl_xor(rs, ms);
      lrowv[i] = lrowv[i] * corr[i] + rs;
      mrow[i] = mn;
    }
#pragma unroll
    for (int nd = 0; nd < 4; ++nd) {
      f32x4 o = oacc[nd];
      o[0] *= corr[0]; o[1] *= corr[1]; o[2] *= corr[2]; o[3] *= corr[3];
      oacc[nd] = o;
    }

    // --- P -> LDS (wave-local)
#pragma unroll
    for (int n = 0; n < 4; ++n)
#pragma unroll
      for (int i = 0; i < 4; ++i)
        Ps[wid][(4 * g + i) * 72 + n * 16 + lr] = f2bf(pvv[n][i]);
    asm volatile("s_waitcnt lgkmcnt(0)" ::: "memory");

    // --- PV: ctx[q][d] += P[q][k] V^T[d][k]
#pragma unroll
    for (int f = 0; f < 2; ++f) {
      bf16x8 pa = *(const bf16x8*)&Ps[wid][lr * 72 + f * 32 + 8 * g];
#pragma unroll
      for (int nd = 0; nd < 4; ++nd) {
        int dr = nd * 16 + lr;
        bf16x8 vb = *(const bf16x8*)&Vts[cur][dr * 64 + (((f * 4 + g) ^ (dr & 7)) * 8)];
        oacc[nd] = mfma16(pa, vb, oacc[nd]);
      }
    }
    __syncthreads();   // next tile landed (vmcnt0); reads of cur done (lgkm0)
    cur ^= 1;
  }

  // epilogue: ctx = oacc / l
  u16* Op = Ob + (size_t)bh * 65536 + (size_t)(qt * 128 + wid * 16) * 64;
#pragma unroll
  for (int nd = 0; nd < 4; ++nd)
#pragma unroll
    for (int i = 0; i < 4; ++i)
      Op[(4 * g + i) * 64 + nd * 16 + lr] = f2bf(oacc[nd][i] / lrowv[i]);
}

// ---------------- LayerNorm in-place over rows of out [4096][1024] ----------------
__global__ __launch_bounds__(256) void ln_kernel(
    float* __restrict__ out, const float* __restrict__ gamma, const float* __restrict__ beta)
{
  int row = blockIdx.x, tid = threadIdx.x;
  int lane = tid & 63, wid = tid >> 6;
  f32x4 v = *(const f32x4*)&out[(size_t)row * 1024 + tid * 4];
  float s = v[0] + v[1] + v[2] + v[3];
  float q = v[0] * v[0] + v[1] * v[1] + v[2] * v[2] + v[3] * v[3];
#pragma unroll
  for (int ms = 1; ms < 64; ms <<= 1) { s += __shfl_xor(s, ms); q += __shfl_xor(q, ms); }
  __shared__ float red[8];
  if (lane == 0) { red[wid] = s; red[wid + 4] = q; }
  __syncthreads();
  s = red[0] + red[1] + red[2] + red[3];
  q = red[4] + red[5] + red[6] + red[7];
  float mu = s * (1.f / 1024.f);
  float var = q * (1.f / 1024.f) - mu * mu;
  float inv = rsqrtf(var + 1e-5f);
  f32x4 g4 = *(const f32x4*)&gamma[tid * 4];
  f32x4 b4 = *(const f32x4*)&beta[tid * 4];
  f32x4 o;
#pragma unroll
  for (int j = 0; j < 4; ++j) o[j] = (v[j] - mu) * inv * g4[j] + b4[j];
  *(f32x4*)&out[(size_t)row * 1024 + tid * 4] = o;
}

// ---------------- launch ----------------
extern "C" void kernel_launch(void* const* d_in, const int* in_sizes, int n_in,
                              void* d_out, int out_size, void* d_ws, size_t ws_size,
                              hipStream_t stream) {
  const float* x     = (const float*)d_in[0];
  const float* Wq    = (const float*)d_in[1];
  const float* bq    = (const float*)d_in[2];
  const float* Wk    = (const float*)d_in[3];
  const float* bk    = (const float*)d_in[4];
  const float* Wv    = (const float*)d_in[5];
  const float* bv    = (const float*)d_in[6];
  const float* Wo    = (const float*)d_in[7];
  const float* bo    = (const float*)d_in[8];
  const float* gamma = (const float*)d_in[9];
  const float* beta  = (const float*)d_in[10];
  float* out = (float*)d_out;

  char* ws = (char*)d_ws;
  u16*   xb  = (u16*)ws;                                   // 8MB  [4096][1024] bf16 (reused as ctx)
  u16*   wb  = (u16*)(ws + (8u << 20));                    // 8MB  Wq|Wk|Wv|Wo bf16
  float* bc  = (float*)(ws + (16u << 20));                 // 12KB bq|bk|bv
  u16*   qkv = (u16*)(ws + (16u << 20) + 16384);           // 24MB Q | K | V^T bf16
  u16*   ctx = xb;                                         // overlay: xb dead after QKV GEMM

  prep_kernel<<<8195, 256, 0, stream>>>(x, Wq, Wk, Wv, Wo, bq, bk, bv, xb, wb, bc);

  // QKV: M=4096 x N=3072 -> grid 768 (bm=(bid&7)+8*((bid>>3)&3), bn=bid>>5)
  gemm_p4<0><<<768, 256, 0, stream>>>(xb, wb, bc, nullptr, qkv, nullptr);

  attn_kernel<<<512, 512, 0, stream>>>(qkv, qkv + 4194304, qkv + 8388608, ctx);

  // out-proj: M=4096 x N=1024 -> grid 256
  gemm_p4<1><<<256, 256, 0, stream>>>(ctx, wb + 3 * 1048576, bo, x, nullptr, out);

  ln_kernel<<<4096, 256, 0, stream>>>(out, gamma, beta);
}